// Round 1
// baseline (501.399 us; speedup 1.0000x reference)
//
#include <hip/hip_runtime.h>

// IRREPS = [(256,0),(128,1),(64,2),(32,3)]
// dim = 256 + 384 + 320 + 224 = 1184; float4 units: 296 per row
// group boundaries (elements): [0,256) g0, [256,640) g1, [640,960) g2, [960,1184) g3
// group boundaries (float4):   [0,64)  g0, [64,160)  g1, [160,240) g2, [240,296) g3
// irrep: g0 e -> e; g1 e -> 256+(e-256)/3; g2 e -> 384+(e-640)/5; g3 e -> 448+(e-960)/7

#define DIM   1184
#define NF4   296
#define EPSV  1e-5f

__global__ __launch_bounds__(256) void eln_kernel(
    const float* __restrict__ x,
    const float* __restrict__ weight,
    const float* __restrict__ bias,
    float* __restrict__ out,
    int n_rows)
{
    const int wave = threadIdx.x >> 6;
    const int lane = threadIdx.x & 63;
    const int row  = blockIdx.x * 4 + wave;
    if (row >= n_rows) return;

    const float4* __restrict__ xr = (const float4*)(x + (size_t)row * DIM);
    float4* __restrict__ orow     = (float4*)(out + (size_t)row * DIM);

    float4 v[5];
    float ssum = 0.f, sq0 = 0.f, sq1 = 0.f, sq2 = 0.f, sq3 = 0.f;

#pragma unroll
    for (int it = 0; it < 5; ++it) {
        const int f4 = lane + it * 64;
        if (f4 < NF4) {
            float4 a = xr[f4];
            v[it] = a;
            const float s2 = a.x*a.x + a.y*a.y + a.z*a.z + a.w*a.w;
            if (f4 < 64)       { ssum += a.x + a.y + a.z + a.w; sq0 += s2; }
            else if (f4 < 160) { sq1 += s2; }
            else if (f4 < 240) { sq2 += s2; }
            else               { sq3 += s2; }
        }
    }

    // wave-wide butterfly reduction (64 lanes)
#pragma unroll
    for (int off = 32; off > 0; off >>= 1) {
        ssum += __shfl_xor(ssum, off);
        sq0  += __shfl_xor(sq0,  off);
        sq1  += __shfl_xor(sq1,  off);
        sq2  += __shfl_xor(sq2,  off);
        sq3  += __shfl_xor(sq3,  off);
    }

    const float m   = ssum * (1.f / 256.f);
    const float v0  = fmaxf(sq0 * (1.f / 256.f) - m * m, 0.f);
    const float rn0 = rsqrtf(v0 + EPSV);
    const float rn1 = rsqrtf(sq1 * (1.f / 384.f) + EPSV);
    const float rn2 = rsqrtf(sq2 * (1.f / 320.f) + EPSV);
    const float rn3 = rsqrtf(sq3 * (1.f / 224.f) + EPSV);

#pragma unroll
    for (int it = 0; it < 5; ++it) {
        const int f4 = lane + it * 64;
        if (f4 < NF4) {
            const float4 a = v[it];
            float4 o;
            const int e = f4 * 4;
            if (f4 < 64) {
                o.x = (a.x - m) * rn0 * weight[e + 0] + bias[e + 0];
                o.y = (a.y - m) * rn0 * weight[e + 1] + bias[e + 1];
                o.z = (a.z - m) * rn0 * weight[e + 2] + bias[e + 2];
                o.w = (a.w - m) * rn0 * weight[e + 3] + bias[e + 3];
            } else if (f4 < 160) {
                const int j = e - 256;
                o.x = a.x * rn1 * weight[256 + (j + 0) / 3];
                o.y = a.y * rn1 * weight[256 + (j + 1) / 3];
                o.z = a.z * rn1 * weight[256 + (j + 2) / 3];
                o.w = a.w * rn1 * weight[256 + (j + 3) / 3];
            } else if (f4 < 240) {
                const int j = e - 640;
                o.x = a.x * rn2 * weight[384 + (j + 0) / 5];
                o.y = a.y * rn2 * weight[384 + (j + 1) / 5];
                o.z = a.z * rn2 * weight[384 + (j + 2) / 5];
                o.w = a.w * rn2 * weight[384 + (j + 3) / 5];
            } else {
                const int j = e - 960;
                o.x = a.x * rn3 * weight[448 + (j + 0) / 7];
                o.y = a.y * rn3 * weight[448 + (j + 1) / 7];
                o.z = a.z * rn3 * weight[448 + (j + 2) / 7];
                o.w = a.w * rn3 * weight[448 + (j + 3) / 7];
            }
            orow[f4] = o;
        }
    }
}

extern "C" void kernel_launch(void* const* d_in, const int* in_sizes, int n_in,
                              void* d_out, int out_size, void* d_ws, size_t ws_size,
                              hipStream_t stream)
{
    const float* x      = (const float*)d_in[0];
    const float* weight = (const float*)d_in[1];
    const float* bias   = (const float*)d_in[2];
    float* out          = (float*)d_out;

    const int n_rows = in_sizes[0] / DIM;          // 65536
    const int blocks = (n_rows + 3) / 4;           // 4 rows (waves) per block
    eln_kernel<<<blocks, 256, 0, stream>>>(x, weight, bias, out, n_rows);
}